// Round 1
// baseline (199.747 us; speedup 1.0000x reference)
//
#include <hip/hip_runtime.h>

// ---------------------------------------------------------------------------
// CausalSelfAttention: fake-quant-i4 weights -> QKV gemm -> RMSNorm+RoPE+gain
// -> GQA causal flash attention -> out proj.  All GEMM-shaped work in bf16
// MFMA (16x16x32), fp32 accumulate. B=2 S=2048 H=16 KVH=4 D=64 DIM=1024.
// ---------------------------------------------------------------------------

typedef __bf16 bf16x8 __attribute__((ext_vector_type(8)));
typedef float  f32x4  __attribute__((ext_vector_type(4)));

__device__ __forceinline__ unsigned short f2bf(float f) {
  unsigned int u = __builtin_bit_cast(unsigned int, f);
  u += 0x7FFFu + ((u >> 16) & 1u);          // RNE
  return (unsigned short)(u >> 16);
}

// ---------------- fake_quant_i4 rows -> bf16 -------------------------------
__global__ void quant_rows(const float* __restrict__ src,
                           unsigned short* __restrict__ dst, int ncols) {
  int row = blockIdx.x;
  const float* s = src + (size_t)row * ncols;
  unsigned short* d = dst + (size_t)row * ncols;
  int t = threadIdx.x;
  float v[4]; float mx = 0.f;
#pragma unroll
  for (int i = 0; i < 4; i++) { v[i] = s[t + 256 * i]; mx = fmaxf(mx, fabsf(v[i])); }
#pragma unroll
  for (int m = 1; m < 64; m <<= 1) mx = fmaxf(mx, __shfl_xor(mx, m));
  __shared__ float smx[4];
  if ((t & 63) == 0) smx[t >> 6] = mx;
  __syncthreads();
  mx = fmaxf(fmaxf(smx[0], smx[1]), fmaxf(smx[2], smx[3]));
  mx = fmaxf(mx, 1e-8f);
  float scale = mx / 7.0f;                  // exact div to match jnp
#pragma unroll
  for (int i = 0; i < 4; i++) {
    float q = rintf(v[i] / scale);          // RNE == jnp.round
    q = fminf(fmaxf(q, -7.0f), 7.0f);
    d[t + 256 * i] = f2bf(q * scale);
  }
}

// ---------------- f32 -> bf16 ----------------------------------------------
__global__ void cvt_bf16(const float* __restrict__ src,
                         unsigned short* __restrict__ dst, int n) {
  int i = (blockIdx.x * 256 + threadIdx.x) * 4;
  if (i >= n) return;
  float4 f = *(const float4*)(src + i);
  ushort4 o;
  o.x = f2bf(f.x); o.y = f2bf(f.y); o.z = f2bf(f.z); o.w = f2bf(f.w);
  *(ushort4*)(dst + i) = o;
}

// ---------------- GEMM: C[M,N] = A[M,K] * B[N,K]^T  (bf16 in, f32 out) -----
// 128x128 tile, BK=64, 4 waves (2x2), T2 XOR-swizzled LDS staged via
// global_load_lds with pre-swizzled global source (rule #21).
#define GLDS(g, l)                                                            \
  __builtin_amdgcn_global_load_lds((const __attribute__((address_space(1))) void*)(g), \
                                   (__attribute__((address_space(3))) void*)(l), 16, 0, 0)

__global__ __launch_bounds__(256, 2) void gemm_bt(
    const unsigned short* __restrict__ A, const unsigned short* __restrict__ Bw,
    float* __restrict__ C, int N, int K, int nbn) {
  int bm = blockIdx.x / nbn, bn = blockIdx.x % nbn;
  int tid = threadIdx.x, w = tid >> 6, lane = tid & 63;
  int l15 = lane & 15, lh = lane >> 4;
  __shared__ __align__(16) unsigned short ldsA[128 * 64];
  __shared__ __align__(16) unsigned short ldsB[128 * 64];
  int wr = w >> 1, wc = w & 1;
  f32x4 zero = {0.f, 0.f, 0.f, 0.f};
  f32x4 acc[4][4];
#pragma unroll
  for (int i = 0; i < 4; i++)
#pragma unroll
    for (int j = 0; j < 4; j++) acc[i][j] = zero;

  // staging map: lane covers (row = seg*8 + lane>>3, chunk = (lane&7)^(lane>>3))
  int srow = lane >> 3, schunk = (lane & 7) ^ (lane >> 3);
  const unsigned short* gA0 = A  + (size_t)(bm * 128 + srow) * K + schunk * 8;
  const unsigned short* gB0 = Bw + (size_t)(bn * 128 + srow) * K + schunk * 8;

  int nk = K >> 6;
  for (int kt = 0; kt < nk; kt++) {
    int k0 = kt * 64;
#pragma unroll
    for (int it = 0; it < 4; it++) {
      int seg = w * 4 + it;  // 16 segs x 8 rows
      GLDS(gA0 + (size_t)(seg * 8) * K + k0, (unsigned short*)ldsA + seg * 512);
      GLDS(gB0 + (size_t)(seg * 8) * K + k0, (unsigned short*)ldsB + seg * 512);
    }
    __syncthreads();
#pragma unroll
    for (int ks = 0; ks < 2; ks++) {
      bf16x8 af[4], bfr[4];
#pragma unroll
      for (int fm = 0; fm < 4; fm++) {
        int row = wr * 64 + fm * 16 + l15;
        int slot = (ks * 4 + lh) ^ (row & 7);
        af[fm] = *(const bf16x8*)(ldsA + row * 64 + slot * 8);
      }
#pragma unroll
      for (int fn = 0; fn < 4; fn++) {
        int row = wc * 64 + fn * 16 + l15;
        int slot = (ks * 4 + lh) ^ (row & 7);
        bfr[fn] = *(const bf16x8*)(ldsB + row * 64 + slot * 8);
      }
#pragma unroll
      for (int fm = 0; fm < 4; fm++)
#pragma unroll
        for (int fn = 0; fn < 4; fn++)
          acc[fm][fn] = __builtin_amdgcn_mfma_f32_16x16x32_bf16(af[fm], bfr[fn], acc[fm][fn], 0, 0, 0);
    }
    __syncthreads();
  }
#pragma unroll
  for (int fm = 0; fm < 4; fm++) {
    int r0 = bm * 128 + wr * 64 + fm * 16 + lh * 4;
#pragma unroll
    for (int fn = 0; fn < 4; fn++) {
      int c = bn * 128 + wc * 64 + fn * 16 + l15;
#pragma unroll
      for (int reg = 0; reg < 4; reg++)
        C[(size_t)(r0 + reg) * N + c] = acc[fm][fn][reg];
    }
  }
}

// ---------------- RMSNorm + RoPE + gain for Q,K ----------------------------
// one wave per (token, head-slot); 16 q heads + 4 k heads = 20 tasks/token
__global__ void postproc_qk(const float* __restrict__ qkv,
                            const float* __restrict__ gain,
                            unsigned short* __restrict__ qb,
                            unsigned short* __restrict__ kb) {
  int task = blockIdx.x * 4 + (threadIdx.x >> 6);
  int lane = threadIdx.x & 63;
  int token = task / 20, hh = task % 20;
  int b = token >> 11, s = token & 2047;
  bool isq = hh < 16;
  const float* src = qkv + (size_t)token * 1536 + (isq ? hh * 64 : 1024 + (hh - 16) * 64);
  float x = src[lane];
  float ss = x * x;
#pragma unroll
  for (int m = 1; m < 64; m <<= 1) ss += __shfl_xor(ss, m);
  x *= rsqrtf(ss * (1.0f / 64.0f) + 1.1920929e-7f);
  // rope: inv_freq = 10000^(-i/32)
  int i = lane & 31;
  float invf = expf(-0.28782313662425572f * (float)i);  // ln(10000)/32
  float ang = (float)s * invf;
  float c, sn;
  sincosf(ang, &sn, &c);
  float x1 = __shfl(x, i);
  float x2 = __shfl(x, i + 32);
  float out = (lane < 32) ? (x1 * c + x2 * sn) : (x2 * c - x1 * sn);
  if (isq) {
    out *= gain[hh];
    qb[((size_t)(b * 16 + hh) * 2048 + s) * 64 + lane] = f2bf(out);
  } else {
    kb[((size_t)(b * 4 + (hh - 16)) * 2048 + s) * 64 + lane] = f2bf(out);
  }
}

// ---------------- V transpose: qkv f32 (s,d) -> Vt bf16 (d,s) --------------
__global__ void v_transpose(const float* __restrict__ qkv,
                            unsigned short* __restrict__ vt) {
  int bid = blockIdx.x;
  int st = bid & 31, kvh = (bid >> 5) & 3, b = bid >> 7;
  __shared__ unsigned short tile[64][65];
  int t = threadIdx.x;
  int sl = t >> 2, d0 = (t & 3) * 16;
  const float* src = qkv + (size_t)(b * 2048 + st * 64 + sl) * 1536 + 1280 + kvh * 64 + d0;
#pragma unroll
  for (int j = 0; j < 16; j++) tile[sl][d0 + j] = f2bf(src[j]);
  __syncthreads();
  int d = t >> 2, s0 = (t & 3) * 16;
  unsigned short* dst = vt + ((size_t)(b * 4 + kvh) * 64 + d) * 2048 + st * 64 + s0;
#pragma unroll
  for (int j = 0; j < 16; j++) dst[j] = tile[s0 + j][d];
}

// ---------------- causal flash attention -----------------------------------
// block = (b, h, q-tile of 128); 4 independent waves of 32 q-rows each.
__global__ __launch_bounds__(256, 2) void attn_fwd(
    const unsigned short* __restrict__ qb, const unsigned short* __restrict__ kb,
    const unsigned short* __restrict__ vtb, unsigned short* __restrict__ ob) {
  int bid = blockIdx.x;
  int qt = bid & 15, h = (bid >> 4) & 15, b = bid >> 8;
  int w = threadIdx.x >> 6, lane = threadIdx.x & 63;
  int l15 = lane & 15, lh = lane >> 4;
  int q0 = qt * 128 + w * 32;
  int kvh = h >> 2;
  const unsigned short* Q  = qb  + (size_t)(b * 16 + h) * (2048 * 64);
  const unsigned short* Kp = kb  + (size_t)(b * 4 + kvh) * (2048 * 64);
  const unsigned short* Vt = vtb + (size_t)(b * 4 + kvh) * (64 * 2048);

  bf16x8 qf[2][2];
#pragma unroll
  for (int fm = 0; fm < 2; fm++)
#pragma unroll
    for (int ks = 0; ks < 2; ks++)
      qf[fm][ks] = *(const bf16x8*)(Q + (q0 + fm * 16 + l15) * 64 + ks * 32 + lh * 8);

  f32x4 zero = {0.f, 0.f, 0.f, 0.f};
  f32x4 o[2][4];
  float mrun[2][4], lrun[2][4];
#pragma unroll
  for (int fm = 0; fm < 2; fm++)
#pragma unroll
    for (int r = 0; r < 4; r++) {
      mrun[fm][r] = -3.0e38f; lrun[fm][r] = 0.f;
      o[fm][r] = zero;  // (reusing r as fn index: both 0..3)
    }

  __shared__ __align__(16) unsigned short plds_all[4][32 * 88];
  unsigned short* plds = plds_all[w];

  int ntiles = (q0 + 95) >> 6;
  for (int t = 0; t < ntiles; t++) {
    int kv0 = t * 64;
    f32x4 sc[2][4];
#pragma unroll
    for (int fm = 0; fm < 2; fm++)
#pragma unroll
      for (int fn = 0; fn < 4; fn++) sc[fm][fn] = zero;
#pragma unroll
    for (int ks = 0; ks < 2; ks++) {
      bf16x8 kf[4];
#pragma unroll
      for (int fn = 0; fn < 4; fn++)
        kf[fn] = *(const bf16x8*)(Kp + (kv0 + fn * 16 + l15) * 64 + ks * 32 + lh * 8);
#pragma unroll
      for (int fm = 0; fm < 2; fm++)
#pragma unroll
        for (int fn = 0; fn < 4; fn++)
          sc[fm][fn] = __builtin_amdgcn_mfma_f32_16x16x32_bf16(qf[fm][ks], kf[fn], sc[fm][fn], 0, 0, 0);
    }
    bool needmask = (kv0 + 63 > q0);
    float pmax[2][4];
#pragma unroll
    for (int fm = 0; fm < 2; fm++)
#pragma unroll
      for (int r = 0; r < 4; r++) pmax[fm][r] = -3.0e38f;
#pragma unroll
    for (int fm = 0; fm < 2; fm++)
#pragma unroll
      for (int fn = 0; fn < 4; fn++)
#pragma unroll
        for (int r = 0; r < 4; r++) {
          float s = sc[fm][fn][r] * 0.125f;
          if (needmask) {
            int col = kv0 + fn * 16 + l15;
            int row = q0 + fm * 16 + lh * 4 + r;
            if (col > row) s = -3.0e38f;
          }
          sc[fm][fn][r] = s;
          pmax[fm][r] = fmaxf(pmax[fm][r], s);
        }
#pragma unroll
    for (int fm = 0; fm < 2; fm++)
#pragma unroll
      for (int r = 0; r < 4; r++) {
        float p = pmax[fm][r];
        p = fmaxf(p, __shfl_xor(p, 1));
        p = fmaxf(p, __shfl_xor(p, 2));
        p = fmaxf(p, __shfl_xor(p, 4));
        p = fmaxf(p, __shfl_xor(p, 8));
        float mnew = fmaxf(mrun[fm][r], p);
        float corr = __expf(mrun[fm][r] - mnew);
        mrun[fm][r] = mnew;
        lrun[fm][r] *= corr;
#pragma unroll
        for (int fn = 0; fn < 4; fn++) o[fm][fn][r] *= corr;
      }
    float rsum[2][4] = {};
#pragma unroll
    for (int fm = 0; fm < 2; fm++)
#pragma unroll
      for (int fn = 0; fn < 4; fn++)
#pragma unroll
        for (int r = 0; r < 4; r++) {
          float p = __expf(sc[fm][fn][r] - mrun[fm][r]);
          rsum[fm][r] += p;
          plds[(fm * 16 + lh * 4 + r) * 88 + fn * 16 + l15] = f2bf(p);
        }
#pragma unroll
    for (int fm = 0; fm < 2; fm++)
#pragma unroll
      for (int r = 0; r < 4; r++) {
        float p = rsum[fm][r];
        p += __shfl_xor(p, 1); p += __shfl_xor(p, 2);
        p += __shfl_xor(p, 4); p += __shfl_xor(p, 8);
        lrun[fm][r] += p;
      }
    asm volatile("s_waitcnt lgkmcnt(0)" ::: "memory");
#pragma unroll
    for (int ks = 0; ks < 2; ks++) {
      bf16x8 vf[4], pf[2];
#pragma unroll
      for (int fn = 0; fn < 4; fn++)
        vf[fn] = *(const bf16x8*)(Vt + (fn * 16 + l15) * 2048 + kv0 + ks * 32 + lh * 8);
#pragma unroll
      for (int fm = 0; fm < 2; fm++)
        pf[fm] = *(const bf16x8*)(plds + (fm * 16 + l15) * 88 + ks * 32 + lh * 8);
#pragma unroll
      for (int fm = 0; fm < 2; fm++)
#pragma unroll
        for (int fn = 0; fn < 4; fn++)
          o[fm][fn] = __builtin_amdgcn_mfma_f32_16x16x32_bf16(pf[fm], vf[fn], o[fm][fn], 0, 0, 0);
    }
  }
#pragma unroll
  for (int fm = 0; fm < 2; fm++)
#pragma unroll
    for (int r = 0; r < 4; r++) {
      float inv = 1.0f / lrun[fm][r];
      int row = q0 + fm * 16 + lh * 4 + r;
#pragma unroll
      for (int fn = 0; fn < 4; fn++) {
        int c = fn * 16 + l15;
        ob[(size_t)(b * 2048 + row) * 1024 + h * 64 + c] = f2bf(o[fm][fn][r] * inv);
      }
    }
}

// ---------------------------------------------------------------------------
extern "C" void kernel_launch(void* const* d_in, const int* in_sizes, int n_in,
                              void* d_out, int out_size, void* d_ws, size_t ws_size,
                              hipStream_t stream) {
  const float* x    = (const float*)d_in[0];
  const float* w_q  = (const float*)d_in[1];
  const float* w_k  = (const float*)d_in[2];
  const float* w_v  = (const float*)d_in[3];
  const float* w_p  = (const float*)d_in[4];
  const float* gain = (const float*)d_in[5];
  float* out = (float*)d_out;

  char* ws = (char*)d_ws;
  unsigned short* x_bf  = (unsigned short*)ws;                   //  8 MB
  unsigned short* wqkv  = (unsigned short*)(ws + (8u << 20));    //  3 MB
  unsigned short* wp    = (unsigned short*)(ws + (11u << 20));   //  2 MB
  float*          qkv   = (float*)(ws + (13u << 20));            // 24 MB
  unsigned short* qbuf  = (unsigned short*)(ws + (37u << 20));   //  8 MB
  unsigned short* kbuf  = (unsigned short*)(ws + (45u << 20));   //  2 MB
  unsigned short* vtbuf = (unsigned short*)(ws + (47u << 20));   //  2 MB
  unsigned short* aout  = (unsigned short*)(ws + (49u << 20));   //  8 MB

  quant_rows<<<1024, 256, 0, stream>>>(w_q, wqkv, 1024);
  quant_rows<<<256, 256, 0, stream>>>(w_k, wqkv + 1024 * 1024, 1024);
  quant_rows<<<256, 256, 0, stream>>>(w_v, wqkv + 1280 * 1024, 1024);
  quant_rows<<<1024, 256, 0, stream>>>(w_p, wp, 1024);
  cvt_bf16<<<4096, 256, 0, stream>>>(x, x_bf, 4194304);
  // fused QKV gemm: M=4096, N=1536, K=1024
  gemm_bt<<<32 * 12, 256, 0, stream>>>(x_bf, wqkv, qkv, 1536, 1024, 12);
  postproc_qk<<<20480, 256, 0, stream>>>(qkv, gain, qbuf, kbuf);
  v_transpose<<<256, 256, 0, stream>>>(qkv, vtbuf);
  attn_fwd<<<512, 256, 0, stream>>>(qbuf, kbuf, vtbuf, aout);
  // out proj: M=4096, N=1024, K=1024
  gemm_bt<<<32 * 8, 256, 0, stream>>>(aout, wp, out, 1024, 1024, 8);
}